// Round 3
// baseline (1454.569 us; speedup 1.0000x reference)
//
#include <hip/hip_runtime.h>
#include <math.h>
#include <stdint.h>

#define EMB 128
#define HID 256
#define ED 16
#define NGRAPH 512
#define NLAYER 3

typedef unsigned short ushort_t;
typedef __attribute__((ext_vector_type(8))) short short8;
typedef __attribute__((ext_vector_type(4))) float fx4;

__device__ __forceinline__ ushort_t f2b(float f){
  unsigned int u = __builtin_bit_cast(unsigned int, f);
  unsigned int r = u + 0x7FFFu + ((u >> 16) & 1u);
  return (ushort_t)(r >> 16);
}

// ---- init virtual node (broadcast vn_emb row) ----
__global__ void k_init_vn(float* __restrict__ vn, const float* __restrict__ vn_emb){
  int idx = blockIdx.x * 256 + threadIdx.x;            // NGRAPH*EMB threads
  vn[idx] = vn_emb[idx & (EMB - 1)];
}

// ---- pre-transpose MLP weights f32 -> bf16 [N][K] for MFMA B-operand ----
__global__ void k_transw(const float* __restrict__ w1, const float* __restrict__ w2,
                         ushort_t* __restrict__ w1t, ushort_t* __restrict__ w2t){
  int idx = blockIdx.x * 256 + threadIdx.x;
  if (idx >= NLAYER * EMB * HID) return;
  int l = idx / (EMB * HID);
  int r = idx % (EMB * HID);
  { int k = r / HID, n = r % HID; w1t[(l * HID + n) * EMB + k] = f2b(w1[idx]); }
  { int k = r / EMB, n = r % EMB; w2t[(l * EMB + n) * HID + k] = f2b(w2[idx]); }
}

// ---- CSR build: count + rank ----
__global__ void k_count(const int* __restrict__ dst, int* __restrict__ counts,
                        int* __restrict__ rankv, int E){
  int e = blockIdx.x * 256 + threadIdx.x;
  if (e >= E) return;
  rankv[e] = atomicAdd(&counts[dst[e]], 1);
}

// ---- 3-kernel exclusive scan over counts[N] -> offs[N] ----
__global__ void k_scanA(const int* __restrict__ counts, int* __restrict__ offs,
                        int* __restrict__ bsum, int N){
  __shared__ int sdata[256];
  int t = threadIdx.x;
  int base = blockIdx.x * 2048 + t * 8;
  int v[8]; int s = 0;
  #pragma unroll
  for (int j = 0; j < 8; j++){
    int idx = base + j;
    v[j] = (idx < N) ? counts[idx] : 0;
    s += v[j];
  }
  sdata[t] = s; __syncthreads();
  for (int off = 1; off < 256; off <<= 1){
    int x = (t >= off) ? sdata[t - off] : 0;
    __syncthreads();
    sdata[t] += x;
    __syncthreads();
  }
  int incl = sdata[t];
  int run = incl - s;   // exclusive prefix of this thread's chunk
  #pragma unroll
  for (int j = 0; j < 8; j++){
    int idx = base + j;
    if (idx < N) offs[idx] = run;
    run += v[j];
  }
  if (t == 255) bsum[blockIdx.x] = incl;
}

__global__ void k_scanB(const int* __restrict__ bsum, int* __restrict__ boff, int nb){
  __shared__ int sdata[256];
  int t = threadIdx.x;
  int v = (t < nb) ? bsum[t] : 0;
  sdata[t] = v; __syncthreads();
  for (int off = 1; off < 256; off <<= 1){
    int x = (t >= off) ? sdata[t - off] : 0;
    __syncthreads();
    sdata[t] += x;
    __syncthreads();
  }
  if (t < nb) boff[t] = sdata[t] - v;
}

__global__ void k_scanC(int* __restrict__ offs, const int* __restrict__ boff, int N, int E){
  int i = blockIdx.x * 256 + threadIdx.x;
  if (i < N) offs[i] += boff[i >> 11];
  else if (i == N) offs[N] = E;
}

__global__ void k_fill(const int* __restrict__ dst, const int* __restrict__ rankv,
                       const int* __restrict__ offs, int* __restrict__ eid, int E){
  int e = blockIdx.x * 256 + threadIdx.x;
  if (e >= E) return;
  eid[offs[dst[e]] + rankv[e]] = e;
}

// ---- h_in = h + vn[batch]  (f32, h may alias h_in: same-element in-place) ----
__global__ void k_hin(const float* __restrict__ h, const int* __restrict__ batch,
                      const float* __restrict__ vn, float* __restrict__ h_in, int N){
  int idx = blockIdx.x * 256 + threadIdx.x;
  if (idx >= N * 32) return;
  int node = idx >> 5;
  int c = (idx & 31) * 4;
  float4 hv = *(const float4*)(h + (size_t)node * EMB + c);
  int b = batch[node];
  float4 v = *(const float4*)(vn + b * EMB + c);
  float4 o; o.x = hv.x + v.x; o.y = hv.y + v.y; o.z = hv.z + v.z; o.w = hv.w + v.w;
  *(float4*)(h_in + (size_t)node * EMB + c) = o;
}

// ---- pull-style GIN aggregation: z0 = bf16(h_in + sum_{e->node} relu(h_in[src]+edge_emb)) ----
__global__ void k_agg(const float* __restrict__ h_in, const float* __restrict__ edge_attr,
                      const int* __restrict__ src, const int* __restrict__ eid,
                      const int* __restrict__ offs, const float* __restrict__ We,
                      const float* __restrict__ be, ushort_t* __restrict__ z0, int N){
  int lane = threadIdx.x & 63;
  int wid = (blockIdx.x * blockDim.x + threadIdx.x) >> 6;
  int nw = (gridDim.x * blockDim.x) >> 6;
  int c0 = lane * 2;
  // edge-encoder weight columns c0,c0+1 in registers (f32)
  float w0[ED], w1[ED];
  #pragma unroll
  for (int k = 0; k < ED; k++){
    w0[k] = We[k * EMB + c0];
    w1[k] = We[k * EMB + c0 + 1];
  }
  float be0 = be[c0], be1 = be[c0 + 1];
  for (int node = wid; node < N; node += nw){
    int s0 = offs[node], s1 = offs[node + 1];
    float a0 = 0.f, a1 = 0.f;
    for (int j = s0; j < s1; j++){
      int e = eid[j];
      int s = src[e];
      const float4* ea = (const float4*)(edge_attr + (size_t)e * ED);
      float4 u0 = ea[0], u1 = ea[1], u2 = ea[2], u3 = ea[3];
      float2 hv = *(const float2*)(h_in + (size_t)s * EMB + c0);
      float f[ED] = {u0.x, u0.y, u0.z, u0.w, u1.x, u1.y, u1.z, u1.w,
                     u2.x, u2.y, u2.z, u2.w, u3.x, u3.y, u3.z, u3.w};
      float e0 = be0, e1 = be1;
      #pragma unroll
      for (int k = 0; k < ED; k++){
        e0 = fmaf(f[k], w0[k], e0);
        e1 = fmaf(f[k], w1[k], e1);
      }
      a0 += fmaxf(hv.x + e0, 0.f);
      a1 += fmaxf(hv.y + e1, 0.f);
    }
    float2 hn = *(const float2*)(h_in + (size_t)node * EMB + c0);
    unsigned int outv = (unsigned int)f2b(hn.x + a0) | ((unsigned int)f2b(hn.y + a1) << 16);
    *(unsigned int*)(z0 + (size_t)node * EMB + c0) = outv;
  }
}

// ---- fused MLP: out = bn(relu(z0@W1+b1)@W2+b2)(+relu) + h_in ; 16 rows/block ----
// h_in/out are the SAME buffer (d_out): each block reads only its own 16 rows
// for the residual, then writes the same rows. No cross-block hazard: k_agg
// (which reads all rows) completed before this kernel launches.
__global__ __launch_bounds__(256) void k_mlp(const ushort_t* __restrict__ A,
                                             const ushort_t* __restrict__ w1t,
                                             const float* __restrict__ b1,
                                             const ushort_t* __restrict__ w2t,
                                             const float* __restrict__ b2,
                                             const float* __restrict__ gamma,
                                             const float* __restrict__ beta,
                                             float* __restrict__ hio,
                                             float inv, int do_relu){
  __shared__ ushort_t ts[16][264];   // hidden tile, +8 pad => only 2-way LDS aliasing (free)
  int w = threadIdx.x >> 6, lane = threadIdx.x & 63;
  int m = lane & 15, q = lane >> 4;
  int row_base = blockIdx.x * 16;
  // ---- GEMM1: [16,128] @ [128,256] -> hidden tile ----
  fx4 acc[4];
  #pragma unroll
  for (int t = 0; t < 4; t++) acc[t] = fx4{0.f, 0.f, 0.f, 0.f};
  #pragma unroll
  for (int k0 = 0; k0 < EMB; k0 += 32){
    short8 a = *(const short8*)(A + (size_t)(row_base + m) * EMB + k0 + q * 8);
    #pragma unroll
    for (int t = 0; t < 4; t++){
      short8 b = *(const short8*)(w1t + (size_t)(w * 64 + t * 16 + m) * EMB + k0 + q * 8);
      acc[t] = __builtin_amdgcn_mfma_f32_16x16x32_bf16(a, b, acc[t], 0, 0, 0);
    }
  }
  #pragma unroll
  for (int t = 0; t < 4; t++){
    int c = w * 64 + t * 16 + m;
    float bv = b1[c];
    #pragma unroll
    for (int i = 0; i < 4; i++){
      float v = fmaxf(acc[t][i] + bv, 0.f);
      ts[q * 4 + i][c] = f2b(v);
    }
  }
  __syncthreads();
  // ---- GEMM2: [16,256] @ [256,128] + epilogue ----
  fx4 acc2[2];
  #pragma unroll
  for (int t = 0; t < 2; t++) acc2[t] = fx4{0.f, 0.f, 0.f, 0.f};
  #pragma unroll
  for (int k0 = 0; k0 < HID; k0 += 32){
    short8 a = *(const short8*)(&ts[m][k0 + q * 8]);
    #pragma unroll
    for (int t = 0; t < 2; t++){
      short8 b = *(const short8*)(w2t + (size_t)(w * 32 + t * 16 + m) * HID + k0 + q * 8);
      acc2[t] = __builtin_amdgcn_mfma_f32_16x16x32_bf16(a, b, acc2[t], 0, 0, 0);
    }
  }
  #pragma unroll
  for (int t = 0; t < 2; t++){
    int c = w * 32 + t * 16 + m;
    float bv = b2[c];
    float sc = gamma[c] * inv;
    float bt = beta[c];
    #pragma unroll
    for (int i = 0; i < 4; i++){
      int r = row_base + q * 4 + i;
      float v = acc2[t][i] + bv;
      v = v * sc + bt;
      if (do_relu) v = fmaxf(v, 0.f);
      float* p = hio + (size_t)r * EMB + c;
      v += *p;
      *p = v;
    }
  }
}

// ---- vt = segment_sum(h_in, batch) + vn  (batch sorted -> binary search) ----
__global__ void k_vt(const float* __restrict__ h_in, const int* __restrict__ batch,
                     const float* __restrict__ vn, float* __restrict__ vt, int N){
  int g = blockIdx.x, c = threadIdx.x;   // 128 threads
  int lo = 0, hi = N;
  while (lo < hi){ int mid = (lo + hi) >> 1; if (batch[mid] < g) lo = mid + 1; else hi = mid; }
  int st = lo;
  lo = 0; hi = N; int g1 = g + 1;
  while (lo < hi){ int mid = (lo + hi) >> 1; if (batch[mid] < g1) lo = mid + 1; else hi = mid; }
  int en = lo;
  float s = 0.f;
  for (int i = st; i < en; i++) s += h_in[(size_t)i * EMB + c];
  vt[g * EMB + c] = s + vn[g * EMB + c];
}

// ---- vn MLP (f32 VALU, tiny): vn_next = vn_cur + relu(bn1(relu(bn0(vt@w1+b1))@w2+b2)) ----
__global__ void k_vnmlp(const float* __restrict__ vt,
                        const float* __restrict__ w1, const float* __restrict__ b1,
                        const float* __restrict__ g1, const float* __restrict__ be1,
                        const float* __restrict__ w2, const float* __restrict__ b2,
                        const float* __restrict__ g2, const float* __restrict__ be2,
                        const float* __restrict__ vnc, float* __restrict__ vnn, float inv){
  __shared__ float vs[EMB];
  __shared__ float ms[HID];
  int g = blockIdx.x, t = threadIdx.x;   // 256 threads
  if (t < EMB) vs[t] = vt[g * EMB + t];
  __syncthreads();
  float acc = b1[t];
  #pragma unroll 4
  for (int k = 0; k < EMB; k++) acc = fmaf(vs[k], w1[k * HID + t], acc);
  acc = acc * (g1[t] * inv) + be1[t];
  ms[t] = fmaxf(acc, 0.f);
  __syncthreads();
  if (t < EMB){
    float a2 = b2[t];
    #pragma unroll 4
    for (int k = 0; k < HID; k++) a2 = fmaf(ms[k], w2[k * EMB + t], a2);
    a2 = a2 * (g2[t] * inv) + be2[t];
    vnn[g * EMB + t] = vnc[g * EMB + t] + fmaxf(a2, 0.f);
  }
}

extern "C" void kernel_launch(void* const* d_in, const int* in_sizes, int n_in,
                              void* d_out, int out_size, void* d_ws, size_t ws_size,
                              hipStream_t stream){
  const float* in_feat   = (const float*)d_in[0];
  const float* edge_attr = (const float*)d_in[1];
  const int*   eidx      = (const int*)d_in[2];
  const int*   batch     = (const int*)d_in[3];
  const float* vn_emb    = (const float*)d_in[4];
  const float* cew = (const float*)d_in[5];
  const float* ceb = (const float*)d_in[6];
  const float* cw1 = (const float*)d_in[7];
  const float* cb1 = (const float*)d_in[8];
  const float* cw2 = (const float*)d_in[9];
  const float* cb2 = (const float*)d_in[10];
  const float* bng = (const float*)d_in[11];
  const float* bnb = (const float*)d_in[12];
  const float* vw1 = (const float*)d_in[13];
  const float* vb1 = (const float*)d_in[14];
  const float* vg1 = (const float*)d_in[15];
  const float* vbe1 = (const float*)d_in[16];
  const float* vw2 = (const float*)d_in[17];
  const float* vb2 = (const float*)d_in[18];
  const float* vg2 = (const float*)d_in[19];
  const float* vbe2 = (const float*)d_in[20];
  float* out = (float*)d_out;

  int N = in_sizes[0] / EMB;
  int E = in_sizes[2] / 2;
  const int* src = eidx;
  const int* dst = eidx + E;

  char* ws = (char*)d_ws;
  auto alloc = [&](size_t bytes) -> char* {
    char* p = ws; ws += (bytes + 255) & ~(size_t)255; return p;
  };
  ushort_t* z0    = (ushort_t*)alloc((size_t)N * EMB * 2);
  float*    vn0   = (float*)alloc((size_t)NGRAPH * EMB * 4);
  float*    vn1   = (float*)alloc((size_t)NGRAPH * EMB * 4);
  float*    vt    = (float*)alloc((size_t)NGRAPH * EMB * 4);
  int*      counts = (int*)alloc((size_t)N * 4);
  int*      rankv  = (int*)alloc((size_t)E * 4);
  int*      offs   = (int*)alloc(((size_t)N + 1) * 4);
  int*      eid    = (int*)alloc((size_t)E * 4);
  int*      bsum   = (int*)alloc(256 * 4);
  int*      boff   = (int*)alloc(256 * 4);
  ushort_t* w1t = (ushort_t*)alloc((size_t)NLAYER * HID * EMB * 2);
  ushort_t* w2t = (ushort_t*)alloc((size_t)NLAYER * EMB * HID * 2);
  float* vnbuf[2] = {vn0, vn1};

  float inv = 1.0f / sqrtf(1.0f + 1e-5f);

  hipMemsetAsync(counts, 0, (size_t)N * 4, stream);
  k_init_vn<<<NGRAPH * EMB / 256, 256, 0, stream>>>(vn0, vn_emb);
  k_transw<<<(NLAYER * EMB * HID + 255) / 256, 256, 0, stream>>>(cw1, cw2, w1t, w2t);
  k_count<<<(E + 255) / 256, 256, 0, stream>>>(dst, counts, rankv, E);
  int nsb = (N + 2047) / 2048;
  k_scanA<<<nsb, 256, 0, stream>>>(counts, offs, bsum, N);
  k_scanB<<<1, 256, 0, stream>>>(bsum, boff, nsb);
  k_scanC<<<(N + 1 + 255) / 256, 256, 0, stream>>>(offs, boff, N, E);
  k_fill<<<(E + 255) / 256, 256, 0, stream>>>(dst, rankv, offs, eid, E);

  for (int l = 0; l < NLAYER; l++){
    const float* vnc = vnbuf[l & 1];
    float* vnn = vnbuf[(l + 1) & 1];
    const float* h = (l == 0) ? in_feat : out;
    // h_in materialized f32 in-place in d_out
    k_hin<<<(N * 32 + 255) / 256, 256, 0, stream>>>(h, batch, vnc, out, N);
    k_agg<<<4096, 256, 0, stream>>>(out, edge_attr, src, eid, offs,
                                    cew + (size_t)l * ED * EMB, ceb + (size_t)l * EMB, z0, N);
    if (l < NLAYER - 1){
      // vt/vn-update must read h_in (d_out) BEFORE k_mlp overwrites it
      k_vt<<<NGRAPH, EMB, 0, stream>>>(out, batch, vnc, vt, N);
      k_vnmlp<<<NGRAPH, HID, 0, stream>>>(vt,
                                          vw1 + (size_t)l * EMB * HID, vb1 + (size_t)l * HID,
                                          vg1 + (size_t)l * HID, vbe1 + (size_t)l * HID,
                                          vw2 + (size_t)l * HID * EMB, vb2 + (size_t)l * EMB,
                                          vg2 + (size_t)l * EMB, vbe2 + (size_t)l * EMB,
                                          vnc, vnn, inv);
    }
    k_mlp<<<(N + 15) / 16, 256, 0, stream>>>(z0, w1t + (size_t)l * HID * EMB, cb1 + (size_t)l * HID,
                                             w2t + (size_t)l * EMB * HID, cb2 + (size_t)l * EMB,
                                             bng + (size_t)l * EMB, bnb + (size_t)l * EMB,
                                             out, inv, (l < NLAYER - 1) ? 1 : 0);
  }
}

// Round 4
// 1220.930 us; speedup vs baseline: 1.1914x; 1.1914x over previous
//
#include <hip/hip_runtime.h>
#include <math.h>
#include <stdint.h>

#define EMB 128
#define HID 256
#define ED 16
#define NGRAPH 512
#define NLAYER 3
#define VT_CHUNK 256

typedef unsigned short ushort_t;
typedef __attribute__((ext_vector_type(8))) short short8;
typedef __attribute__((ext_vector_type(4))) float fx4;

__device__ __forceinline__ ushort_t f2b(float f){
  unsigned int u = __builtin_bit_cast(unsigned int, f);
  unsigned int r = u + 0x7FFFu + ((u >> 16) & 1u);
  return (ushort_t)(r >> 16);
}

// ---- init virtual node (broadcast vn_emb row) ----
__global__ void k_init_vn(float* __restrict__ vn, const float* __restrict__ vn_emb){
  int idx = blockIdx.x * 256 + threadIdx.x;            // NGRAPH*EMB threads
  vn[idx] = vn_emb[idx & (EMB - 1)];
}

// ---- pre-transpose MLP weights f32 -> bf16 [N][K] for MFMA B-operand ----
__global__ void k_transw(const float* __restrict__ w1, const float* __restrict__ w2,
                         ushort_t* __restrict__ w1t, ushort_t* __restrict__ w2t){
  int idx = blockIdx.x * 256 + threadIdx.x;
  if (idx >= NLAYER * EMB * HID) return;
  int l = idx / (EMB * HID);
  int r = idx % (EMB * HID);
  { int k = r / HID, n = r % HID; w1t[(l * HID + n) * EMB + k] = f2b(w1[idx]); }
  { int k = r / EMB, n = r % EMB; w2t[(l * EMB + n) * HID + k] = f2b(w2[idx]); }
}

// ---- CSR build: count + rank ----
__global__ void k_count(const int* __restrict__ dst, int* __restrict__ counts,
                        int* __restrict__ rankv, int E){
  int e = blockIdx.x * 256 + threadIdx.x;
  if (e >= E) return;
  rankv[e] = atomicAdd(&counts[dst[e]], 1);
}

// ---- 3-kernel exclusive scan over counts[N] -> offs[N] ----
__global__ void k_scanA(const int* __restrict__ counts, int* __restrict__ offs,
                        int* __restrict__ bsum, int N){
  __shared__ int sdata[256];
  int t = threadIdx.x;
  int base = blockIdx.x * 2048 + t * 8;
  int v[8]; int s = 0;
  #pragma unroll
  for (int j = 0; j < 8; j++){
    int idx = base + j;
    v[j] = (idx < N) ? counts[idx] : 0;
    s += v[j];
  }
  sdata[t] = s; __syncthreads();
  for (int off = 1; off < 256; off <<= 1){
    int x = (t >= off) ? sdata[t - off] : 0;
    __syncthreads();
    sdata[t] += x;
    __syncthreads();
  }
  int incl = sdata[t];
  int run = incl - s;   // exclusive prefix of this thread's chunk
  #pragma unroll
  for (int j = 0; j < 8; j++){
    int idx = base + j;
    if (idx < N) offs[idx] = run;
    run += v[j];
  }
  if (t == 255) bsum[blockIdx.x] = incl;
}

__global__ void k_scanB(const int* __restrict__ bsum, int* __restrict__ boff, int nb){
  __shared__ int sdata[256];
  int t = threadIdx.x;
  int v = (t < nb) ? bsum[t] : 0;
  sdata[t] = v; __syncthreads();
  for (int off = 1; off < 256; off <<= 1){
    int x = (t >= off) ? sdata[t - off] : 0;
    __syncthreads();
    sdata[t] += x;
    __syncthreads();
  }
  if (t < nb) boff[t] = sdata[t] - v;
}

__global__ void k_scanC(int* __restrict__ offs, const int* __restrict__ boff, int N, int E){
  int i = blockIdx.x * 256 + threadIdx.x;
  if (i < N) offs[i] += boff[i >> 11];
  else if (i == N) offs[N] = E;
}

// ---- fill packed CSR: se[j] = (src, eid) — removes one gather indirection ----
__global__ void k_fill(const int* __restrict__ src, const int* __restrict__ dst,
                       const int* __restrict__ rankv, const int* __restrict__ offs,
                       int2* __restrict__ se, int E){
  int e = blockIdx.x * 256 + threadIdx.x;
  if (e >= E) return;
  se[offs[dst[e]] + rankv[e]] = make_int2(src[e], e);
}

// ---- h_in = h + vn[batch]  (f32, h may alias h_in: same-element in-place) ----
__global__ void k_hin(const float* __restrict__ h, const int* __restrict__ batch,
                      const float* __restrict__ vn, float* __restrict__ h_in, int N){
  int idx = blockIdx.x * 256 + threadIdx.x;
  if (idx >= N * 32) return;
  int node = idx >> 5;
  int c = (idx & 31) * 4;
  float4 hv = *(const float4*)(h + (size_t)node * EMB + c);
  int b = batch[node];
  float4 v = *(const float4*)(vn + b * EMB + c);
  float4 o; o.x = hv.x + v.x; o.y = hv.y + v.y; o.z = hv.z + v.z; o.w = hv.w + v.w;
  *(float4*)(h_in + (size_t)node * EMB + c) = o;
}

__device__ __forceinline__ float2 edge_msg(const float* __restrict__ edge_attr, int e,
                                           const float* __restrict__ w0,
                                           const float* __restrict__ w1,
                                           float be0, float be1){
  const float4* ea = (const float4*)(edge_attr + (size_t)e * ED);
  float4 u0 = ea[0], u1 = ea[1], u2 = ea[2], u3 = ea[3];
  float f[ED] = {u0.x, u0.y, u0.z, u0.w, u1.x, u1.y, u1.z, u1.w,
                 u2.x, u2.y, u2.z, u2.w, u3.x, u3.y, u3.z, u3.w};
  float e0 = be0, e1 = be1;
  #pragma unroll
  for (int k = 0; k < ED; k++){
    e0 = fmaf(f[k], w0[k], e0);
    e1 = fmaf(f[k], w1[k], e1);
  }
  return make_float2(e0, e1);
}

// ---- pull-style GIN aggregation, unroll-2 for MLP:
//      z0 = bf16(h_in + sum_{e->node} relu(h_in[src]+edge_emb)) ----
__global__ void k_agg(const float* __restrict__ h_in, const float* __restrict__ edge_attr,
                      const int2* __restrict__ se, const int* __restrict__ offs,
                      const float* __restrict__ We, const float* __restrict__ be,
                      ushort_t* __restrict__ z0, int N){
  int lane = threadIdx.x & 63;
  int wid = (blockIdx.x * blockDim.x + threadIdx.x) >> 6;
  int nw = (gridDim.x * blockDim.x) >> 6;
  int c0 = lane * 2;
  // edge-encoder weight columns c0,c0+1 in registers (f32)
  float w0[ED], w1[ED];
  #pragma unroll
  for (int k = 0; k < ED; k++){
    w0[k] = We[k * EMB + c0];
    w1[k] = We[k * EMB + c0 + 1];
  }
  float be0 = be[c0], be1 = be[c0 + 1];
  for (int node = wid; node < N; node += nw){
    int s0 = offs[node], s1 = offs[node + 1];
    float2 hn = *(const float2*)(h_in + (size_t)node * EMB + c0);  // early, independent
    float a0 = 0.f, a1 = 0.f, b0 = 0.f, b1 = 0.f;
    int j = s0;
    for (; j + 1 < s1; j += 2){
      int2 p0 = se[j], p1 = se[j + 1];
      float2 hva = *(const float2*)(h_in + (size_t)p0.x * EMB + c0);
      float2 hvb = *(const float2*)(h_in + (size_t)p1.x * EMB + c0);
      float2 mA = edge_msg(edge_attr, p0.y, w0, w1, be0, be1);
      float2 mB = edge_msg(edge_attr, p1.y, w0, w1, be0, be1);
      a0 += fmaxf(hva.x + mA.x, 0.f);
      a1 += fmaxf(hva.y + mA.y, 0.f);
      b0 += fmaxf(hvb.x + mB.x, 0.f);
      b1 += fmaxf(hvb.y + mB.y, 0.f);
    }
    if (j < s1){
      int2 p0 = se[j];
      float2 hva = *(const float2*)(h_in + (size_t)p0.x * EMB + c0);
      float2 mA = edge_msg(edge_attr, p0.y, w0, w1, be0, be1);
      a0 += fmaxf(hva.x + mA.x, 0.f);
      a1 += fmaxf(hva.y + mA.y, 0.f);
    }
    float r0 = hn.x + a0 + b0;
    float r1 = hn.y + a1 + b1;
    unsigned int outv = (unsigned int)f2b(r0) | ((unsigned int)f2b(r1) << 16);
    *(unsigned int*)(z0 + (size_t)node * EMB + c0) = outv;
  }
}

// ---- fused MLP: out = bn(relu(z0@W1+b1)@W2+b2)(+relu) + h_in ; 16 rows/block ----
// h_in/out are the SAME buffer (d_out): each block reads only its own 16 rows
// for the residual, then writes the same rows. No cross-block hazard: k_agg/k_vt
// (which read all rows) completed before this kernel launches.
__global__ __launch_bounds__(256) void k_mlp(const ushort_t* __restrict__ A,
                                             const ushort_t* __restrict__ w1t,
                                             const float* __restrict__ b1,
                                             const ushort_t* __restrict__ w2t,
                                             const float* __restrict__ b2,
                                             const float* __restrict__ gamma,
                                             const float* __restrict__ beta,
                                             float* __restrict__ hio,
                                             float inv, int do_relu){
  __shared__ ushort_t ts[16][264];   // hidden tile, +8 pad => only 2-way LDS aliasing (free)
  int w = threadIdx.x >> 6, lane = threadIdx.x & 63;
  int m = lane & 15, q = lane >> 4;
  int row_base = blockIdx.x * 16;
  // ---- GEMM1: [16,128] @ [128,256] -> hidden tile ----
  fx4 acc[4];
  #pragma unroll
  for (int t = 0; t < 4; t++) acc[t] = fx4{0.f, 0.f, 0.f, 0.f};
  #pragma unroll
  for (int k0 = 0; k0 < EMB; k0 += 32){
    short8 a = *(const short8*)(A + (size_t)(row_base + m) * EMB + k0 + q * 8);
    #pragma unroll
    for (int t = 0; t < 4; t++){
      short8 b = *(const short8*)(w1t + (size_t)(w * 64 + t * 16 + m) * EMB + k0 + q * 8);
      acc[t] = __builtin_amdgcn_mfma_f32_16x16x32_bf16(a, b, acc[t], 0, 0, 0);
    }
  }
  #pragma unroll
  for (int t = 0; t < 4; t++){
    int c = w * 64 + t * 16 + m;
    float bv = b1[c];
    #pragma unroll
    for (int i = 0; i < 4; i++){
      float v = fmaxf(acc[t][i] + bv, 0.f);
      ts[q * 4 + i][c] = f2b(v);
    }
  }
  __syncthreads();
  // ---- GEMM2: [16,256] @ [256,128] + epilogue ----
  fx4 acc2[2];
  #pragma unroll
  for (int t = 0; t < 2; t++) acc2[t] = fx4{0.f, 0.f, 0.f, 0.f};
  #pragma unroll
  for (int k0 = 0; k0 < HID; k0 += 32){
    short8 a = *(const short8*)(&ts[m][k0 + q * 8]);
    #pragma unroll
    for (int t = 0; t < 2; t++){
      short8 b = *(const short8*)(w2t + (size_t)(w * 32 + t * 16 + m) * HID + k0 + q * 8);
      acc2[t] = __builtin_amdgcn_mfma_f32_16x16x32_bf16(a, b, acc2[t], 0, 0, 0);
    }
  }
  #pragma unroll
  for (int t = 0; t < 2; t++){
    int c = w * 32 + t * 16 + m;
    float bv = b2[c];
    float sc = gamma[c] * inv;
    float bt = beta[c];
    #pragma unroll
    for (int i = 0; i < 4; i++){
      int r = row_base + q * 4 + i;
      float v = acc2[t][i] + bv;
      v = v * sc + bt;
      if (do_relu) v = fmaxf(v, 0.f);
      float* p = hio + (size_t)r * EMB + c;
      v += *p;
      *p = v;
    }
  }
}

// ---- vt init: vt = vn ----
__global__ void k_vt_init(const float* __restrict__ vn, float* __restrict__ vt){
  int idx = blockIdx.x * 256 + threadIdx.x;
  vt[idx] = vn[idx];
}

// ---- vt += segment_sum(h_in, batch): chunked partial sums + boundary atomics.
// 256 threads: wave-uniform node index (c = t&127, half = t>>7), coalesced 256B reads.
__global__ void k_vt(const float* __restrict__ h_in, const int* __restrict__ batch,
                     float* __restrict__ vt, int N){
  int c = threadIdx.x & 127;
  int half = threadIdx.x >> 7;
  int start = blockIdx.x * VT_CHUNK;
  int end = start + VT_CHUNK; if (end > N) end = N;
  float acc = 0.f;
  int curg = batch[start];
  for (int i = start + half; i < end; i += 2){
    int g = batch[i];                       // wave-uniform
    if (g != curg){
      atomicAdd(&vt[curg * EMB + c], acc);
      acc = 0.f;
      curg = g;
    }
    acc += h_in[(size_t)i * EMB + c];
  }
  atomicAdd(&vt[curg * EMB + c], acc);
}

// ---- vn MLP (f32 VALU, tiny): vn_next = vn_cur + relu(bn1(relu(bn0(vt@w1+b1))@w2+b2)) ----
__global__ void k_vnmlp(const float* __restrict__ vt,
                        const float* __restrict__ w1, const float* __restrict__ b1,
                        const float* __restrict__ g1, const float* __restrict__ be1,
                        const float* __restrict__ w2, const float* __restrict__ b2,
                        const float* __restrict__ g2, const float* __restrict__ be2,
                        const float* __restrict__ vnc, float* __restrict__ vnn, float inv){
  __shared__ float vs[EMB];
  __shared__ float ms[HID];
  int g = blockIdx.x, t = threadIdx.x;   // 256 threads
  if (t < EMB) vs[t] = vt[g * EMB + t];
  __syncthreads();
  float acc = b1[t];
  #pragma unroll 4
  for (int k = 0; k < EMB; k++) acc = fmaf(vs[k], w1[k * HID + t], acc);
  acc = acc * (g1[t] * inv) + be1[t];
  ms[t] = fmaxf(acc, 0.f);
  __syncthreads();
  if (t < EMB){
    float a2 = b2[t];
    #pragma unroll 4
    for (int k = 0; k < HID; k++) a2 = fmaf(ms[k], w2[k * EMB + t], a2);
    a2 = a2 * (g2[t] * inv) + be2[t];
    vnn[g * EMB + t] = vnc[g * EMB + t] + fmaxf(a2, 0.f);
  }
}

extern "C" void kernel_launch(void* const* d_in, const int* in_sizes, int n_in,
                              void* d_out, int out_size, void* d_ws, size_t ws_size,
                              hipStream_t stream){
  const float* in_feat   = (const float*)d_in[0];
  const float* edge_attr = (const float*)d_in[1];
  const int*   eidx      = (const int*)d_in[2];
  const int*   batch     = (const int*)d_in[3];
  const float* vn_emb    = (const float*)d_in[4];
  const float* cew = (const float*)d_in[5];
  const float* ceb = (const float*)d_in[6];
  const float* cw1 = (const float*)d_in[7];
  const float* cb1 = (const float*)d_in[8];
  const float* cw2 = (const float*)d_in[9];
  const float* cb2 = (const float*)d_in[10];
  const float* bng = (const float*)d_in[11];
  const float* bnb = (const float*)d_in[12];
  const float* vw1 = (const float*)d_in[13];
  const float* vb1 = (const float*)d_in[14];
  const float* vg1 = (const float*)d_in[15];
  const float* vbe1 = (const float*)d_in[16];
  const float* vw2 = (const float*)d_in[17];
  const float* vb2 = (const float*)d_in[18];
  const float* vg2 = (const float*)d_in[19];
  const float* vbe2 = (const float*)d_in[20];
  float* out = (float*)d_out;

  int N = in_sizes[0] / EMB;
  int E = in_sizes[2] / 2;
  const int* src = eidx;
  const int* dst = eidx + E;

  char* ws = (char*)d_ws;
  auto alloc = [&](size_t bytes) -> char* {
    char* p = ws; ws += (bytes + 255) & ~(size_t)255; return p;
  };
  ushort_t* z0    = (ushort_t*)alloc((size_t)N * EMB * 2);
  float*    vn0   = (float*)alloc((size_t)NGRAPH * EMB * 4);
  float*    vn1   = (float*)alloc((size_t)NGRAPH * EMB * 4);
  float*    vt    = (float*)alloc((size_t)NGRAPH * EMB * 4);
  int*      counts = (int*)alloc((size_t)N * 4);
  int*      rankv  = (int*)alloc((size_t)E * 4);
  int*      offs   = (int*)alloc(((size_t)N + 1) * 4);
  int2*     se     = (int2*)alloc((size_t)E * 8);
  int*      bsum   = (int*)alloc(256 * 4);
  int*      boff   = (int*)alloc(256 * 4);
  ushort_t* w1t = (ushort_t*)alloc((size_t)NLAYER * HID * EMB * 2);
  ushort_t* w2t = (ushort_t*)alloc((size_t)NLAYER * EMB * HID * 2);
  float* vnbuf[2] = {vn0, vn1};

  float inv = 1.0f / sqrtf(1.0f + 1e-5f);

  hipMemsetAsync(counts, 0, (size_t)N * 4, stream);
  k_init_vn<<<NGRAPH * EMB / 256, 256, 0, stream>>>(vn0, vn_emb);
  k_transw<<<(NLAYER * EMB * HID + 255) / 256, 256, 0, stream>>>(cw1, cw2, w1t, w2t);
  k_count<<<(E + 255) / 256, 256, 0, stream>>>(dst, counts, rankv, E);
  int nsb = (N + 2047) / 2048;
  k_scanA<<<nsb, 256, 0, stream>>>(counts, offs, bsum, N);
  k_scanB<<<1, 256, 0, stream>>>(bsum, boff, nsb);
  k_scanC<<<(N + 1 + 255) / 256, 256, 0, stream>>>(offs, boff, N, E);
  k_fill<<<(E + 255) / 256, 256, 0, stream>>>(src, dst, rankv, offs, se, E);

  for (int l = 0; l < NLAYER; l++){
    const float* vnc = vnbuf[l & 1];
    float* vnn = vnbuf[(l + 1) & 1];
    const float* h = (l == 0) ? in_feat : out;
    // h_in materialized f32 in-place in d_out
    k_hin<<<(N * 32 + 255) / 256, 256, 0, stream>>>(h, batch, vnc, out, N);
    k_agg<<<4096, 256, 0, stream>>>(out, edge_attr, se, offs,
                                    cew + (size_t)l * ED * EMB, ceb + (size_t)l * EMB, z0, N);
    if (l < NLAYER - 1){
      // vt/vn-update must read h_in (d_out) BEFORE k_mlp overwrites it
      k_vt_init<<<NGRAPH * EMB / 256, 256, 0, stream>>>(vnc, vt);
      k_vt<<<(N + VT_CHUNK - 1) / VT_CHUNK, 256, 0, stream>>>(out, batch, vt, N);
      k_vnmlp<<<NGRAPH, HID, 0, stream>>>(vt,
                                          vw1 + (size_t)l * EMB * HID, vb1 + (size_t)l * HID,
                                          vg1 + (size_t)l * HID, vbe1 + (size_t)l * HID,
                                          vw2 + (size_t)l * HID * EMB, vb2 + (size_t)l * EMB,
                                          vg2 + (size_t)l * EMB, vbe2 + (size_t)l * EMB,
                                          vnc, vnn, inv);
    }
    k_mlp<<<(N + 15) / 16, 256, 0, stream>>>(z0, w1t + (size_t)l * HID * EMB, cb1 + (size_t)l * HID,
                                             w2t + (size_t)l * EMB * HID, cb2 + (size_t)l * EMB,
                                             bng + (size_t)l * EMB, bnb + (size_t)l * EMB,
                                             out, inv, (l < NLAYER - 1) ? 1 : 0);
  }
}

// Round 5
// 1049.581 us; speedup vs baseline: 1.3859x; 1.1633x over previous
//
#include <hip/hip_runtime.h>
#include <math.h>
#include <stdint.h>

#define EMB 128
#define HID 256
#define ED 16
#define NGRAPH 512
#define NLAYER 3
#define VT_CHUNK 256

typedef unsigned short ushort_t;
typedef __attribute__((ext_vector_type(8))) short short8;
typedef __attribute__((ext_vector_type(4))) float fx4;

__device__ __forceinline__ ushort_t f2b(float f){
  unsigned int u = __builtin_bit_cast(unsigned int, f);
  unsigned int r = u + 0x7FFFu + ((u >> 16) & 1u);
  return (ushort_t)(r >> 16);
}
__device__ __forceinline__ float blo(unsigned int u){
  return __builtin_bit_cast(float, u << 16);
}
__device__ __forceinline__ float bhi(unsigned int u){
  return __builtin_bit_cast(float, u & 0xFFFF0000u);
}

// ---- init virtual node (broadcast vn_emb row) ----
__global__ void k_init_vn(float* __restrict__ vn, const float* __restrict__ vn_emb){
  int idx = blockIdx.x * 256 + threadIdx.x;            // NGRAPH*EMB threads
  vn[idx] = vn_emb[idx & (EMB - 1)];
}

// ---- pre-transpose MLP weights f32 -> bf16 [N][K] for MFMA B-operand ----
__global__ void k_transw(const float* __restrict__ w1, const float* __restrict__ w2,
                         ushort_t* __restrict__ w1t, ushort_t* __restrict__ w2t){
  int idx = blockIdx.x * 256 + threadIdx.x;
  if (idx >= NLAYER * EMB * HID) return;
  int l = idx / (EMB * HID);
  int r = idx % (EMB * HID);
  { int k = r / HID, n = r % HID; w1t[(l * HID + n) * EMB + k] = f2b(w1[idx]); }
  { int k = r / EMB, n = r % EMB; w2t[(l * EMB + n) * HID + k] = f2b(w2[idx]); }
}

// ---- CSR build: count + rank ----
__global__ void k_count(const int* __restrict__ dst, int* __restrict__ counts,
                        int* __restrict__ rankv, int E){
  int e = blockIdx.x * 256 + threadIdx.x;
  if (e >= E) return;
  rankv[e] = atomicAdd(&counts[dst[e]], 1);
}

// ---- 3-kernel exclusive scan over counts[N] -> offs[N] ----
__global__ void k_scanA(const int* __restrict__ counts, int* __restrict__ offs,
                        int* __restrict__ bsum, int N){
  __shared__ int sdata[256];
  int t = threadIdx.x;
  int base = blockIdx.x * 2048 + t * 8;
  int v[8]; int s = 0;
  #pragma unroll
  for (int j = 0; j < 8; j++){
    int idx = base + j;
    v[j] = (idx < N) ? counts[idx] : 0;
    s += v[j];
  }
  sdata[t] = s; __syncthreads();
  for (int off = 1; off < 256; off <<= 1){
    int x = (t >= off) ? sdata[t - off] : 0;
    __syncthreads();
    sdata[t] += x;
    __syncthreads();
  }
  int incl = sdata[t];
  int run = incl - s;   // exclusive prefix of this thread's chunk
  #pragma unroll
  for (int j = 0; j < 8; j++){
    int idx = base + j;
    if (idx < N) offs[idx] = run;
    run += v[j];
  }
  if (t == 255) bsum[blockIdx.x] = incl;
}

__global__ void k_scanB(const int* __restrict__ bsum, int* __restrict__ boff, int nb){
  __shared__ int sdata[256];
  int t = threadIdx.x;
  int v = (t < nb) ? bsum[t] : 0;
  sdata[t] = v; __syncthreads();
  for (int off = 1; off < 256; off <<= 1){
    int x = (t >= off) ? sdata[t - off] : 0;
    __syncthreads();
    sdata[t] += x;
    __syncthreads();
  }
  if (t < nb) boff[t] = sdata[t] - v;
}

__global__ void k_scanC(int* __restrict__ offs, const int* __restrict__ boff, int N, int E){
  int i = blockIdx.x * 256 + threadIdx.x;
  if (i < N) offs[i] += boff[i >> 11];
  else if (i == N) offs[N] = E;
}

// ---- CSR reorder: ea2[pos] = bf16(edge_attr[e]); srcs[pos] = src[e].
// Makes k_agg's edge stream fully sequential; drops the eid indirection. ----
__global__ void k_reorder(const float* __restrict__ ea, const int* __restrict__ src,
                          const int* __restrict__ dst, const int* __restrict__ rankv,
                          const int* __restrict__ offs, ushort_t* __restrict__ ea2,
                          int* __restrict__ srcs, int E){
  int e = blockIdx.x * 256 + threadIdx.x;
  if (e >= E) return;
  int pos = offs[dst[e]] + rankv[e];
  srcs[pos] = src[e];
  const float4* p = (const float4*)(ea + (size_t)e * ED);
  float4 f0 = p[0], f1 = p[1], f2 = p[2], f3 = p[3];
  float f[ED] = {f0.x, f0.y, f0.z, f0.w, f1.x, f1.y, f1.z, f1.w,
                 f2.x, f2.y, f2.z, f2.w, f3.x, f3.y, f3.z, f3.w};
  unsigned int u[8];
  #pragma unroll
  for (int k = 0; k < 8; k++)
    u[k] = (unsigned int)f2b(f[2 * k]) | ((unsigned int)f2b(f[2 * k + 1]) << 16);
  uint4* q = (uint4*)(ea2 + (size_t)pos * ED);
  q[0] = make_uint4(u[0], u[1], u[2], u[3]);
  q[1] = make_uint4(u[4], u[5], u[6], u[7]);
}

// ---- h_in = h + vn[batch]  (layer 0 only): writes f32 d_out AND bf16 hb ----
__global__ void k_hin(const float* __restrict__ h, const int* __restrict__ batch,
                      const float* __restrict__ vn, float* __restrict__ h_in,
                      ushort_t* __restrict__ hb, int N){
  int idx = blockIdx.x * 256 + threadIdx.x;
  if (idx >= N * 32) return;
  int node = idx >> 5;
  int c = (idx & 31) * 4;
  float4 hv = *(const float4*)(h + (size_t)node * EMB + c);
  int b = batch[node];
  float4 v = *(const float4*)(vn + b * EMB + c);
  float4 o; o.x = hv.x + v.x; o.y = hv.y + v.y; o.z = hv.z + v.z; o.w = hv.w + v.w;
  *(float4*)(h_in + (size_t)node * EMB + c) = o;
  uint2 ob;
  ob.x = (unsigned int)f2b(o.x) | ((unsigned int)f2b(o.y) << 16);
  ob.y = (unsigned int)f2b(o.z) | ((unsigned int)f2b(o.w) << 16);
  *(uint2*)(hb + (size_t)node * EMB + c) = ob;
}

__device__ __forceinline__ float2 edge_msg_b(const ushort_t* __restrict__ ea2, int j,
                                             const float* __restrict__ w0,
                                             const float* __restrict__ w1,
                                             float be0, float be1){
  const uint4* p = (const uint4*)(ea2 + (size_t)j * ED);
  uint4 u0 = p[0], u1 = p[1];
  unsigned int uu[8] = {u0.x, u0.y, u0.z, u0.w, u1.x, u1.y, u1.z, u1.w};
  float e0 = be0, e1 = be1;
  #pragma unroll
  for (int k = 0; k < 8; k++){
    float lo = blo(uu[k]), hi = bhi(uu[k]);
    e0 = fmaf(lo, w0[2 * k], e0);     e1 = fmaf(lo, w1[2 * k], e1);
    e0 = fmaf(hi, w0[2 * k + 1], e0); e1 = fmaf(hi, w1[2 * k + 1], e1);
  }
  return make_float2(e0, e1);
}

// ---- pull-style GIN aggregation, unroll-4, bf16 gathers + sequential edge stream:
//      z0 = bf16(h_in + sum_{e->node} relu(h_in[src]+edge_emb)) ----
__global__ void k_agg(const ushort_t* __restrict__ hb, const ushort_t* __restrict__ ea2,
                      const int* __restrict__ srcs, const int* __restrict__ offs,
                      const float* __restrict__ We, const float* __restrict__ be,
                      ushort_t* __restrict__ z0, int N){
  int lane = threadIdx.x & 63;
  int wid = (blockIdx.x * blockDim.x + threadIdx.x) >> 6;
  int nw = (gridDim.x * blockDim.x) >> 6;
  int c0 = lane * 2;
  float w0[ED], w1[ED];
  #pragma unroll
  for (int k = 0; k < ED; k++){
    w0[k] = We[k * EMB + c0];
    w1[k] = We[k * EMB + c0 + 1];
  }
  float be0 = be[c0], be1 = be[c0 + 1];
  for (int node = wid; node < N; node += nw){
    int s0 = offs[node], s1 = offs[node + 1];
    unsigned int hn = *(const unsigned int*)(hb + (size_t)node * EMB + c0);
    float x0 = 0.f, x1 = 0.f, x2 = 0.f, x3 = 0.f;   // col c0 partials
    float y0 = 0.f, y1 = 0.f, y2 = 0.f, y3 = 0.f;   // col c0+1 partials
    int j = s0;
    for (; j + 3 < s1; j += 4){
      int sA = srcs[j], sB = srcs[j + 1], sC = srcs[j + 2], sD = srcs[j + 3];
      unsigned int gA = *(const unsigned int*)(hb + (size_t)sA * EMB + c0);
      unsigned int gB = *(const unsigned int*)(hb + (size_t)sB * EMB + c0);
      unsigned int gC = *(const unsigned int*)(hb + (size_t)sC * EMB + c0);
      unsigned int gD = *(const unsigned int*)(hb + (size_t)sD * EMB + c0);
      float2 mA = edge_msg_b(ea2, j,     w0, w1, be0, be1);
      float2 mB = edge_msg_b(ea2, j + 1, w0, w1, be0, be1);
      float2 mC = edge_msg_b(ea2, j + 2, w0, w1, be0, be1);
      float2 mD = edge_msg_b(ea2, j + 3, w0, w1, be0, be1);
      x0 += fmaxf(blo(gA) + mA.x, 0.f);  y0 += fmaxf(bhi(gA) + mA.y, 0.f);
      x1 += fmaxf(blo(gB) + mB.x, 0.f);  y1 += fmaxf(bhi(gB) + mB.y, 0.f);
      x2 += fmaxf(blo(gC) + mC.x, 0.f);  y2 += fmaxf(bhi(gC) + mC.y, 0.f);
      x3 += fmaxf(blo(gD) + mD.x, 0.f);  y3 += fmaxf(bhi(gD) + mD.y, 0.f);
    }
    for (; j < s1; j++){
      int sA = srcs[j];
      unsigned int gA = *(const unsigned int*)(hb + (size_t)sA * EMB + c0);
      float2 mA = edge_msg_b(ea2, j, w0, w1, be0, be1);
      x0 += fmaxf(blo(gA) + mA.x, 0.f);  y0 += fmaxf(bhi(gA) + mA.y, 0.f);
    }
    float r0 = blo(hn) + ((x0 + x1) + (x2 + x3));
    float r1 = bhi(hn) + ((y0 + y1) + (y2 + y3));
    unsigned int outv = (unsigned int)f2b(r0) | ((unsigned int)f2b(r1) << 16);
    *(unsigned int*)(z0 + (size_t)node * EMB + c0) = outv;
  }
}

// ---- fused MLP + next-layer h_in:
// v = bn(relu(z0@W1+b1)@W2+b2)(+relu) + h_in  [; + vn_next[batch] if add_vn]
// writes f32 d_out (and bf16 hb for the next k_agg if write_hb).
// h_in/out are the SAME buffer (d_out): each block touches only its own 16 rows. ----
__global__ __launch_bounds__(256) void k_mlp(const ushort_t* __restrict__ A,
                                             const ushort_t* __restrict__ w1t,
                                             const float* __restrict__ b1,
                                             const ushort_t* __restrict__ w2t,
                                             const float* __restrict__ b2,
                                             const float* __restrict__ gamma,
                                             const float* __restrict__ beta,
                                             float* __restrict__ hio,
                                             const int* __restrict__ batch,
                                             const float* __restrict__ vn_next,
                                             ushort_t* __restrict__ hb_out,
                                             float inv, int do_relu, int add_vn){
  __shared__ ushort_t ts[16][264];   // hidden tile, +8 pad => only 2-way LDS aliasing (free)
  int w = threadIdx.x >> 6, lane = threadIdx.x & 63;
  int m = lane & 15, q = lane >> 4;
  int row_base = blockIdx.x * 16;
  // ---- GEMM1: [16,128] @ [128,256] -> hidden tile ----
  fx4 acc[4];
  #pragma unroll
  for (int t = 0; t < 4; t++) acc[t] = fx4{0.f, 0.f, 0.f, 0.f};
  #pragma unroll
  for (int k0 = 0; k0 < EMB; k0 += 32){
    short8 a = *(const short8*)(A + (size_t)(row_base + m) * EMB + k0 + q * 8);
    #pragma unroll
    for (int t = 0; t < 4; t++){
      short8 b = *(const short8*)(w1t + (size_t)(w * 64 + t * 16 + m) * EMB + k0 + q * 8);
      acc[t] = __builtin_amdgcn_mfma_f32_16x16x32_bf16(a, b, acc[t], 0, 0, 0);
    }
  }
  #pragma unroll
  for (int t = 0; t < 4; t++){
    int c = w * 64 + t * 16 + m;
    float bv = b1[c];
    #pragma unroll
    for (int i = 0; i < 4; i++){
      float v = fmaxf(acc[t][i] + bv, 0.f);
      ts[q * 4 + i][c] = f2b(v);
    }
  }
  __syncthreads();
  // ---- GEMM2: [16,256] @ [256,128] + epilogue ----
  fx4 acc2[2];
  #pragma unroll
  for (int t = 0; t < 2; t++) acc2[t] = fx4{0.f, 0.f, 0.f, 0.f};
  #pragma unroll
  for (int k0 = 0; k0 < HID; k0 += 32){
    short8 a = *(const short8*)(&ts[m][k0 + q * 8]);
    #pragma unroll
    for (int t = 0; t < 2; t++){
      short8 b = *(const short8*)(w2t + (size_t)(w * 32 + t * 16 + m) * HID + k0 + q * 8);
      acc2[t] = __builtin_amdgcn_mfma_f32_16x16x32_bf16(a, b, acc2[t], 0, 0, 0);
    }
  }
  float bv2[2], sc2[2], bt2[2];
  #pragma unroll
  for (int t = 0; t < 2; t++){
    int c = w * 32 + t * 16 + m;
    bv2[t] = b2[c]; sc2[t] = gamma[c] * inv; bt2[t] = beta[c];
  }
  #pragma unroll
  for (int i = 0; i < 4; i++){
    int r = row_base + q * 4 + i;
    int bidx = add_vn ? batch[r] : 0;
    #pragma unroll
    for (int t = 0; t < 2; t++){
      int c = w * 32 + t * 16 + m;
      float v = acc2[t][i] + bv2[t];
      v = v * sc2[t] + bt2[t];
      if (do_relu) v = fmaxf(v, 0.f);
      float* p = hio + (size_t)r * EMB + c;
      v += *p;
      if (add_vn) v += vn_next[bidx * EMB + c];
      *p = v;
      if (add_vn) hb_out[(size_t)r * EMB + c] = f2b(v);
    }
  }
}

// ---- vt init: vt = vn ----
__global__ void k_vt_init(const float* __restrict__ vn, float* __restrict__ vt){
  int idx = blockIdx.x * 256 + threadIdx.x;
  vt[idx] = vn[idx];
}

// ---- vt += segment_sum(h_in, batch): chunked partial sums + boundary atomics ----
__global__ void k_vt(const float* __restrict__ h_in, const int* __restrict__ batch,
                     float* __restrict__ vt, int N){
  int c = threadIdx.x & 127;
  int half = threadIdx.x >> 7;
  int start = blockIdx.x * VT_CHUNK;
  int end = start + VT_CHUNK; if (end > N) end = N;
  float acc = 0.f;
  int curg = batch[start];
  for (int i = start + half; i < end; i += 2){
    int g = batch[i];                       // wave-uniform
    if (g != curg){
      atomicAdd(&vt[curg * EMB + c], acc);
      acc = 0.f;
      curg = g;
    }
    acc += h_in[(size_t)i * EMB + c];
  }
  atomicAdd(&vt[curg * EMB + c], acc);
}

// ---- vn MLP (f32 VALU, tiny): vn_next = vn_cur + relu(bn1(relu(bn0(vt@w1+b1))@w2+b2)) ----
__global__ void k_vnmlp(const float* __restrict__ vt,
                        const float* __restrict__ w1, const float* __restrict__ b1,
                        const float* __restrict__ g1, const float* __restrict__ be1,
                        const float* __restrict__ w2, const float* __restrict__ b2,
                        const float* __restrict__ g2, const float* __restrict__ be2,
                        const float* __restrict__ vnc, float* __restrict__ vnn, float inv){
  __shared__ float vs[EMB];
  __shared__ float ms[HID];
  int g = blockIdx.x, t = threadIdx.x;   // 256 threads
  if (t < EMB) vs[t] = vt[g * EMB + t];
  __syncthreads();
  float acc = b1[t];
  #pragma unroll 4
  for (int k = 0; k < EMB; k++) acc = fmaf(vs[k], w1[k * HID + t], acc);
  acc = acc * (g1[t] * inv) + be1[t];
  ms[t] = fmaxf(acc, 0.f);
  __syncthreads();
  if (t < EMB){
    float a2 = b2[t];
    #pragma unroll 4
    for (int k = 0; k < HID; k++) a2 = fmaf(ms[k], w2[k * EMB + t], a2);
    a2 = a2 * (g2[t] * inv) + be2[t];
    vnn[g * EMB + t] = vnc[g * EMB + t] + fmaxf(a2, 0.f);
  }
}

extern "C" void kernel_launch(void* const* d_in, const int* in_sizes, int n_in,
                              void* d_out, int out_size, void* d_ws, size_t ws_size,
                              hipStream_t stream){
  const float* in_feat   = (const float*)d_in[0];
  const float* edge_attr = (const float*)d_in[1];
  const int*   eidx      = (const int*)d_in[2];
  const int*   batch     = (const int*)d_in[3];
  const float* vn_emb    = (const float*)d_in[4];
  const float* cew = (const float*)d_in[5];
  const float* ceb = (const float*)d_in[6];
  const float* cw1 = (const float*)d_in[7];
  const float* cb1 = (const float*)d_in[8];
  const float* cw2 = (const float*)d_in[9];
  const float* cb2 = (const float*)d_in[10];
  const float* bng = (const float*)d_in[11];
  const float* bnb = (const float*)d_in[12];
  const float* vw1 = (const float*)d_in[13];
  const float* vb1 = (const float*)d_in[14];
  const float* vg1 = (const float*)d_in[15];
  const float* vbe1 = (const float*)d_in[16];
  const float* vw2 = (const float*)d_in[17];
  const float* vb2 = (const float*)d_in[18];
  const float* vg2 = (const float*)d_in[19];
  const float* vbe2 = (const float*)d_in[20];
  float* out = (float*)d_out;

  int N = in_sizes[0] / EMB;
  int E = in_sizes[2] / 2;
  const int* src = eidx;
  const int* dst = eidx + E;

  char* ws = (char*)d_ws;
  auto alloc = [&](size_t bytes) -> char* {
    char* p = ws; ws += (bytes + 255) & ~(size_t)255; return p;
  };
  ushort_t* z0    = (ushort_t*)alloc((size_t)N * EMB * 2);
  ushort_t* hb    = (ushort_t*)alloc((size_t)N * EMB * 2);
  ushort_t* ea2   = (ushort_t*)alloc((size_t)E * ED * 2);
  int*      srcs  = (int*)alloc((size_t)E * 4);
  float*    vn0   = (float*)alloc((size_t)NGRAPH * EMB * 4);
  float*    vn1   = (float*)alloc((size_t)NGRAPH * EMB * 4);
  float*    vt    = (float*)alloc((size_t)NGRAPH * EMB * 4);
  int*      counts = (int*)alloc((size_t)N * 4);
  int*      rankv  = (int*)alloc((size_t)E * 4);
  int*      offs   = (int*)alloc(((size_t)N + 1) * 4);
  int*      bsum   = (int*)alloc(256 * 4);
  int*      boff   = (int*)alloc(256 * 4);
  ushort_t* w1t = (ushort_t*)alloc((size_t)NLAYER * HID * EMB * 2);
  ushort_t* w2t = (ushort_t*)alloc((size_t)NLAYER * EMB * HID * 2);
  float* vnbuf[2] = {vn0, vn1};

  float inv = 1.0f / sqrtf(1.0f + 1e-5f);

  hipMemsetAsync(counts, 0, (size_t)N * 4, stream);
  k_init_vn<<<NGRAPH * EMB / 256, 256, 0, stream>>>(vn0, vn_emb);
  k_transw<<<(NLAYER * EMB * HID + 255) / 256, 256, 0, stream>>>(cw1, cw2, w1t, w2t);
  k_count<<<(E + 255) / 256, 256, 0, stream>>>(dst, counts, rankv, E);
  int nsb = (N + 2047) / 2048;
  k_scanA<<<nsb, 256, 0, stream>>>(counts, offs, bsum, N);
  k_scanB<<<1, 256, 0, stream>>>(bsum, boff, nsb);
  k_scanC<<<(N + 1 + 255) / 256, 256, 0, stream>>>(offs, boff, N, E);
  k_reorder<<<(E + 255) / 256, 256, 0, stream>>>(edge_attr, src, dst, rankv, offs, ea2, srcs, E);

  for (int l = 0; l < NLAYER; l++){
    const float* vnc = vnbuf[l & 1];
    float* vnn = vnbuf[(l + 1) & 1];
    if (l == 0)
      k_hin<<<(N * 32 + 255) / 256, 256, 0, stream>>>(in_feat, batch, vnc, out, hb, N);
    k_agg<<<4096, 256, 0, stream>>>(hb, ea2, srcs, offs,
                                    cew + (size_t)l * ED * EMB, ceb + (size_t)l * EMB, z0, N);
    if (l < NLAYER - 1){
      // vt/vn-update must read h_in (d_out) BEFORE k_mlp overwrites it
      k_vt_init<<<NGRAPH * EMB / 256, 256, 0, stream>>>(vnc, vt);
      k_vt<<<(N + VT_CHUNK - 1) / VT_CHUNK, 256, 0, stream>>>(out, batch, vt, N);
      k_vnmlp<<<NGRAPH, HID, 0, stream>>>(vt,
                                          vw1 + (size_t)l * EMB * HID, vb1 + (size_t)l * HID,
                                          vg1 + (size_t)l * HID, vbe1 + (size_t)l * HID,
                                          vw2 + (size_t)l * HID * EMB, vb2 + (size_t)l * EMB,
                                          vg2 + (size_t)l * EMB, vbe2 + (size_t)l * EMB,
                                          vnc, vnn, inv);
    }
    // epilogue: for l<2 produce next layer's h_in (f32 d_out + bf16 hb)
    k_mlp<<<(N + 15) / 16, 256, 0, stream>>>(z0, w1t + (size_t)l * HID * EMB, cb1 + (size_t)l * HID,
                                             w2t + (size_t)l * EMB * HID, cb2 + (size_t)l * EMB,
                                             bng + (size_t)l * EMB, bnb + (size_t)l * EMB,
                                             out, batch, vnn, hb, inv,
                                             (l < NLAYER - 1) ? 1 : 0, (l < NLAYER - 1) ? 1 : 0);
  }
}

// Round 7
// 899.240 us; speedup vs baseline: 1.6176x; 1.1672x over previous
//
#include <hip/hip_runtime.h>
#include <math.h>
#include <stdint.h>

#define EMB 128
#define HID 256
#define ED 16
#define NGRAPH 512
#define NLAYER 3
#define VT_CHUNK 256

typedef unsigned short ushort_t;
typedef __attribute__((ext_vector_type(8))) short short8;
typedef __attribute__((ext_vector_type(4))) float fx4;

__device__ __forceinline__ ushort_t f2b(float f){
  unsigned int u = __builtin_bit_cast(unsigned int, f);
  unsigned int r = u + 0x7FFFu + ((u >> 16) & 1u);
  return (ushort_t)(r >> 16);
}
__device__ __forceinline__ float b2f(ushort_t u){
  return __builtin_bit_cast(float, ((unsigned int)u) << 16);
}
__device__ __forceinline__ float blo(unsigned int u){
  return __builtin_bit_cast(float, u << 16);
}
__device__ __forceinline__ float bhi(unsigned int u){
  return __builtin_bit_cast(float, u & 0xFFFF0000u);
}

// ---- init virtual node (broadcast vn_emb row) ----
__global__ void k_init_vn(float* __restrict__ vn, const float* __restrict__ vn_emb){
  int idx = blockIdx.x * 256 + threadIdx.x;            // NGRAPH*EMB threads
  vn[idx] = vn_emb[idx & (EMB - 1)];
}

// ---- pre-transpose MLP weights f32 -> bf16 [N][K] for MFMA B-operand ----
__global__ void k_transw(const float* __restrict__ w1, const float* __restrict__ w2,
                         ushort_t* __restrict__ w1t, ushort_t* __restrict__ w2t){
  int idx = blockIdx.x * 256 + threadIdx.x;
  if (idx >= NLAYER * EMB * HID) return;
  int l = idx / (EMB * HID);
  int r = idx % (EMB * HID);
  { int k = r / HID, n = r % HID; w1t[(l * HID + n) * EMB + k] = f2b(w1[idx]); }
  { int k = r / EMB, n = r % EMB; w2t[(l * EMB + n) * HID + k] = f2b(w2[idx]); }
}

// ---- CSR build: count + rank ----
__global__ void k_count(const int* __restrict__ dst, int* __restrict__ counts,
                        int* __restrict__ rankv, int E){
  int e = blockIdx.x * 256 + threadIdx.x;
  if (e >= E) return;
  rankv[e] = atomicAdd(&counts[dst[e]], 1);
}

// ---- 3-kernel exclusive scan over counts[N] -> offs[N] ----
__global__ void k_scanA(const int* __restrict__ counts, int* __restrict__ offs,
                        int* __restrict__ bsum, int N){
  __shared__ int sdata[256];
  int t = threadIdx.x;
  int base = blockIdx.x * 2048 + t * 8;
  int v[8]; int s = 0;
  #pragma unroll
  for (int j = 0; j < 8; j++){
    int idx = base + j;
    v[j] = (idx < N) ? counts[idx] : 0;
    s += v[j];
  }
  sdata[t] = s; __syncthreads();
  for (int off = 1; off < 256; off <<= 1){
    int x = (t >= off) ? sdata[t - off] : 0;
    __syncthreads();
    sdata[t] += x;
    __syncthreads();
  }
  int incl = sdata[t];
  int run = incl - s;   // exclusive prefix of this thread's chunk
  #pragma unroll
  for (int j = 0; j < 8; j++){
    int idx = base + j;
    if (idx < N) offs[idx] = run;
    run += v[j];
  }
  if (t == 255) bsum[blockIdx.x] = incl;
}

__global__ void k_scanB(const int* __restrict__ bsum, int* __restrict__ boff, int nb){
  __shared__ int sdata[256];
  int t = threadIdx.x;
  int v = (t < nb) ? bsum[t] : 0;
  sdata[t] = v; __syncthreads();
  for (int off = 1; off < 256; off <<= 1){
    int x = (t >= off) ? sdata[t - off] : 0;
    __syncthreads();
    sdata[t] += x;
    __syncthreads();
  }
  if (t < nb) boff[t] = sdata[t] - v;
}

__global__ void k_scanC(int* __restrict__ offs, const int* __restrict__ boff, int N, int E){
  int i = blockIdx.x * 256 + threadIdx.x;
  if (i < N) offs[i] += boff[i >> 11];
  else if (i == N) offs[N] = E;
}

// ---- CSR reorder: ea2[pos] = bf16(edge_attr[e]); srcs[pos] = src[e] ----
__global__ void k_reorder(const float* __restrict__ ea, const int* __restrict__ src,
                          const int* __restrict__ dst, const int* __restrict__ rankv,
                          const int* __restrict__ offs, ushort_t* __restrict__ ea2,
                          int* __restrict__ srcs, int E){
  int e = blockIdx.x * 256 + threadIdx.x;
  if (e >= E) return;
  int pos = offs[dst[e]] + rankv[e];
  srcs[pos] = src[e];
  const float4* p = (const float4*)(ea + (size_t)e * ED);
  float4 f0 = p[0], f1 = p[1], f2 = p[2], f3 = p[3];
  float f[ED] = {f0.x, f0.y, f0.z, f0.w, f1.x, f1.y, f1.z, f1.w,
                 f2.x, f2.y, f2.z, f2.w, f3.x, f3.y, f3.z, f3.w};
  unsigned int u[8];
  #pragma unroll
  for (int k = 0; k < 8; k++)
    u[k] = (unsigned int)f2b(f[2 * k]) | ((unsigned int)f2b(f[2 * k + 1]) << 16);
  uint4* q = (uint4*)(ea2 + (size_t)pos * ED);
  q[0] = make_uint4(u[0], u[1], u[2], u[3]);
  q[1] = make_uint4(u[4], u[5], u[6], u[7]);
}

// ---- layer-0 h_in = bf16(in_feat + vn[batch]) -> hb only ----
__global__ void k_hin(const float* __restrict__ h, const int* __restrict__ batch,
                      const float* __restrict__ vn, ushort_t* __restrict__ hb, int N){
  int idx = blockIdx.x * 256 + threadIdx.x;
  if (idx >= N * 32) return;
  int node = idx >> 5;
  int c = (idx & 31) * 4;
  float4 hv = *(const float4*)(h + (size_t)node * EMB + c);
  int b = batch[node];
  float4 v = *(const float4*)(vn + b * EMB + c);
  uint2 ob;
  ob.x = (unsigned int)f2b(hv.x + v.x) | ((unsigned int)f2b(hv.y + v.y) << 16);
  ob.y = (unsigned int)f2b(hv.z + v.z) | ((unsigned int)f2b(hv.w + v.w) << 16);
  *(uint2*)(hb + (size_t)node * EMB + c) = ob;
}

__device__ __forceinline__ float2 edge_msg_b(const ushort_t* __restrict__ ea2, int j,
                                             const float* __restrict__ w0,
                                             const float* __restrict__ w1,
                                             float be0, float be1){
  const uint4* p = (const uint4*)(ea2 + (size_t)j * ED);
  uint4 u0 = p[0], u1 = p[1];
  unsigned int uu[8] = {u0.x, u0.y, u0.z, u0.w, u1.x, u1.y, u1.z, u1.w};
  float e0 = be0, e1 = be1;
  #pragma unroll
  for (int k = 0; k < 8; k++){
    float lo = blo(uu[k]), hi = bhi(uu[k]);
    e0 = fmaf(lo, w0[2 * k], e0);     e1 = fmaf(lo, w1[2 * k], e1);
    e0 = fmaf(hi, w0[2 * k + 1], e0); e1 = fmaf(hi, w1[2 * k + 1], e1);
  }
  return make_float2(e0, e1);
}

// ---- pull-style GIN aggregation, unroll-4:
//      z0 = bf16(h_in + sum_{e->node} relu(h_in[src]+edge_emb)) ----
__global__ void k_agg(const ushort_t* __restrict__ hb, const ushort_t* __restrict__ ea2,
                      const int* __restrict__ srcs, const int* __restrict__ offs,
                      const float* __restrict__ We, const float* __restrict__ be,
                      ushort_t* __restrict__ z0, int N){
  int lane = threadIdx.x & 63;
  int wid = (blockIdx.x * blockDim.x + threadIdx.x) >> 6;
  int nw = (gridDim.x * blockDim.x) >> 6;
  int c0 = lane * 2;
  float w0[ED], w1[ED];
  #pragma unroll
  for (int k = 0; k < ED; k++){
    w0[k] = We[k * EMB + c0];
    w1[k] = We[k * EMB + c0 + 1];
  }
  float be0 = be[c0], be1 = be[c0 + 1];
  for (int node = wid; node < N; node += nw){
    int s0 = offs[node], s1 = offs[node + 1];
    unsigned int hn = *(const unsigned int*)(hb + (size_t)node * EMB + c0);
    float x0 = 0.f, x1 = 0.f, x2 = 0.f, x3 = 0.f;
    float y0 = 0.f, y1 = 0.f, y2 = 0.f, y3 = 0.f;
    int j = s0;
    for (; j + 3 < s1; j += 4){
      int sA = srcs[j], sB = srcs[j + 1], sC = srcs[j + 2], sD = srcs[j + 3];
      unsigned int gA = *(const unsigned int*)(hb + (size_t)sA * EMB + c0);
      unsigned int gB = *(const unsigned int*)(hb + (size_t)sB * EMB + c0);
      unsigned int gC = *(const unsigned int*)(hb + (size_t)sC * EMB + c0);
      unsigned int gD = *(const unsigned int*)(hb + (size_t)sD * EMB + c0);
      float2 mA = edge_msg_b(ea2, j,     w0, w1, be0, be1);
      float2 mB = edge_msg_b(ea2, j + 1, w0, w1, be0, be1);
      float2 mC = edge_msg_b(ea2, j + 2, w0, w1, be0, be1);
      float2 mD = edge_msg_b(ea2, j + 3, w0, w1, be0, be1);
      x0 += fmaxf(blo(gA) + mA.x, 0.f);  y0 += fmaxf(bhi(gA) + mA.y, 0.f);
      x1 += fmaxf(blo(gB) + mB.x, 0.f);  y1 += fmaxf(bhi(gB) + mB.y, 0.f);
      x2 += fmaxf(blo(gC) + mC.x, 0.f);  y2 += fmaxf(bhi(gC) + mC.y, 0.f);
      x3 += fmaxf(blo(gD) + mD.x, 0.f);  y3 += fmaxf(bhi(gD) + mD.y, 0.f);
    }
    for (; j < s1; j++){
      int sA = srcs[j];
      unsigned int gA = *(const unsigned int*)(hb + (size_t)sA * EMB + c0);
      float2 mA = edge_msg_b(ea2, j, w0, w1, be0, be1);
      x0 += fmaxf(blo(gA) + mA.x, 0.f);  y0 += fmaxf(bhi(gA) + mA.y, 0.f);
    }
    float r0 = blo(hn) + ((x0 + x1) + (x2 + x3));
    float r1 = bhi(hn) + ((y0 + y1) + (y2 + y3));
    unsigned int outv = (unsigned int)f2b(r0) | ((unsigned int)f2b(r1) << 16);
    *(unsigned int*)(z0 + (size_t)node * EMB + c0) = outv;
  }
}

// ---- fused MLP, register-resident weights, grid-stride over 16-row tiles:
// v = bn(relu(z0@W1+b1)@W2+b2)(+relu) + h_in(bf16 hb) [+ vn_next[batch]]
// l<2:  write hb (bf16) only.   l==2: write d_out (f32) only. ----
__global__ __launch_bounds__(256, 2) void k_mlp(const ushort_t* __restrict__ A,
                                                const ushort_t* __restrict__ w1t,
                                                const float* __restrict__ b1,
                                                const ushort_t* __restrict__ w2t,
                                                const float* __restrict__ b2,
                                                const float* __restrict__ gamma,
                                                const float* __restrict__ beta,
                                                const ushort_t* __restrict__ hb_in,
                                                const int* __restrict__ batch,
                                                const float* __restrict__ vn_next,
                                                ushort_t* __restrict__ hb_out,
                                                float* __restrict__ fout,
                                                float inv, int last, int ntiles){
  __shared__ ushort_t ts[2][16][264];   // double-buffered hidden tile, 1 barrier/tile
  int w = threadIdx.x >> 6, lane = threadIdx.x & 63;
  int m = lane & 15, q = lane >> 4;

  // ---- preload this wave's weight fragments (once per block) ----
  short8 w1f[4][4];   // [k-step][col-tile], cols w*64 + t*16 + m
  #pragma unroll
  for (int kk = 0; kk < 4; kk++)
    #pragma unroll
    for (int t = 0; t < 4; t++)
      w1f[kk][t] = *(const short8*)(w1t + (size_t)(w * 64 + t * 16 + m) * EMB + kk * 32 + q * 8);
  short8 w2f[8][2];   // cols w*32 + t*16 + m
  #pragma unroll
  for (int kk = 0; kk < 8; kk++)
    #pragma unroll
    for (int t = 0; t < 2; t++)
      w2f[kk][t] = *(const short8*)(w2t + (size_t)(w * 32 + t * 16 + m) * HID + kk * 32 + q * 8);

  float bv1[4], bv2[2], sc2[2], bt2[2];
  #pragma unroll
  for (int t = 0; t < 4; t++) bv1[t] = b1[w * 64 + t * 16 + m];
  #pragma unroll
  for (int t = 0; t < 2; t++){
    int c = w * 32 + t * 16 + m;
    bv2[t] = b2[c]; sc2[t] = gamma[c] * inv; bt2[t] = beta[c];
  }

  int p = 0;
  for (int tile = blockIdx.x; tile < ntiles; tile += gridDim.x, p ^= 1){
    int row_base = tile * 16;
    // ---- GEMM1: [16,128] @ [128,256] -> hidden tile (LDS) ----
    fx4 acc[4];
    #pragma unroll
    for (int t = 0; t < 4; t++) acc[t] = fx4{0.f, 0.f, 0.f, 0.f};
    #pragma unroll
    for (int kk = 0; kk < 4; kk++){
      short8 a = *(const short8*)(A + (size_t)(row_base + m) * EMB + kk * 32 + q * 8);
      #pragma unroll
      for (int t = 0; t < 4; t++)
        acc[t] = __builtin_amdgcn_mfma_f32_16x16x32_bf16(a, w1f[kk][t], acc[t], 0, 0, 0);
    }
    #pragma unroll
    for (int t = 0; t < 4; t++){
      int c = w * 64 + t * 16 + m;
      #pragma unroll
      for (int i = 0; i < 4; i++)
        ts[p][q * 4 + i][c] = f2b(fmaxf(acc[t][i] + bv1[t], 0.f));
    }
    __syncthreads();
    // ---- GEMM2: [16,256] @ [256,128] + epilogue ----
    fx4 acc2[2];
    #pragma unroll
    for (int t = 0; t < 2; t++) acc2[t] = fx4{0.f, 0.f, 0.f, 0.f};
    #pragma unroll
    for (int kk = 0; kk < 8; kk++){
      short8 a = *(const short8*)(&ts[p][m][kk * 32 + q * 8]);
      #pragma unroll
      for (int t = 0; t < 2; t++)
        acc2[t] = __builtin_amdgcn_mfma_f32_16x16x32_bf16(a, w2f[kk][t], acc2[t], 0, 0, 0);
    }
    #pragma unroll
    for (int i = 0; i < 4; i++){
      int r = row_base + q * 4 + i;
      int bidx = last ? 0 : batch[r];
      #pragma unroll
      for (int t = 0; t < 2; t++){
        int c = w * 32 + t * 16 + m;
        float v = acc2[t][i] + bv2[t];
        v = v * sc2[t] + bt2[t];
        if (!last) v = fmaxf(v, 0.f);                       // inner-layer relu
        v += b2f(hb_in[(size_t)r * EMB + c]);               // residual
        if (!last){
          v += vn_next[bidx * EMB + c];                     // next layer's vn add
          hb_out[(size_t)r * EMB + c] = f2b(v);
        } else {
          fout[(size_t)r * EMB + c] = v;
        }
      }
    }
  }
}

// ---- vt += segment_sum(hb, batch): chunked partial sums + boundary atomics ----
__global__ void k_vt(const ushort_t* __restrict__ hb, const int* __restrict__ batch,
                     float* __restrict__ vt, int N){
  int c = threadIdx.x & 127;
  int half = threadIdx.x >> 7;
  int start = blockIdx.x * VT_CHUNK;
  int end = start + VT_CHUNK; if (end > N) end = N;
  float acc = 0.f;
  int curg = batch[start];
  for (int i = start + half; i < end; i += 2){
    int g = batch[i];                       // wave-uniform
    if (g != curg){
      atomicAdd(&vt[curg * EMB + c], acc);
      acc = 0.f;
      curg = g;
    }
    acc += b2f(hb[(size_t)i * EMB + c]);
  }
  atomicAdd(&vt[curg * EMB + c], acc);
}

// ---- vn MLP: vn_next = vn_cur + relu(bn1(relu(bn0((vt+vn)@w1+b1))@w2+b2)) ----
__global__ void k_vnmlp(const float* __restrict__ vt,
                        const float* __restrict__ w1, const float* __restrict__ b1,
                        const float* __restrict__ g1, const float* __restrict__ be1,
                        const float* __restrict__ w2, const float* __restrict__ b2,
                        const float* __restrict__ g2, const float* __restrict__ be2,
                        const float* __restrict__ vnc, float* __restrict__ vnn, float inv){
  __shared__ float vs[EMB];
  __shared__ float ms[HID];
  int g = blockIdx.x, t = threadIdx.x;   // 256 threads
  if (t < EMB) vs[t] = vt[g * EMB + t] + vnc[g * EMB + t];
  __syncthreads();
  float acc = b1[t];
  #pragma unroll 4
  for (int k = 0; k < EMB; k++) acc = fmaf(vs[k], w1[k * HID + t], acc);
  acc = acc * (g1[t] * inv) + be1[t];
  ms[t] = fmaxf(acc, 0.f);
  __syncthreads();
  if (t < EMB){
    float a2 = b2[t];
    #pragma unroll 4
    for (int k = 0; k < HID; k++) a2 = fmaf(ms[k], w2[k * EMB + t], a2);
    a2 = a2 * (g2[t] * inv) + be2[t];
    vnn[g * EMB + t] = vnc[g * EMB + t] + fmaxf(a2, 0.f);
  }
}

extern "C" void kernel_launch(void* const* d_in, const int* in_sizes, int n_in,
                              void* d_out, int out_size, void* d_ws, size_t ws_size,
                              hipStream_t stream){
  const float* in_feat   = (const float*)d_in[0];
  const float* edge_attr = (const float*)d_in[1];
  const int*   eidx      = (const int*)d_in[2];
  const int*   batch     = (const int*)d_in[3];
  const float* vn_emb    = (const float*)d_in[4];
  const float* cew = (const float*)d_in[5];
  const float* ceb = (const float*)d_in[6];
  const float* cw1 = (const float*)d_in[7];
  const float* cb1 = (const float*)d_in[8];
  const float* cw2 = (const float*)d_in[9];
  const float* cb2 = (const float*)d_in[10];
  const float* bng = (const float*)d_in[11];
  const float* bnb = (const float*)d_in[12];
  const float* vw1 = (const float*)d_in[13];
  const float* vb1 = (const float*)d_in[14];
  const float* vg1 = (const float*)d_in[15];
  const float* vbe1 = (const float*)d_in[16];
  const float* vw2 = (const float*)d_in[17];
  const float* vb2 = (const float*)d_in[18];
  const float* vg2 = (const float*)d_in[19];
  const float* vbe2 = (const float*)d_in[20];
  float* out = (float*)d_out;

  int N = in_sizes[0] / EMB;
  int E = in_sizes[2] / 2;
  const int* src = eidx;
  const int* dst = eidx + E;

  char* ws = (char*)d_ws;
  auto alloc = [&](size_t bytes) -> char* {
    char* p = ws; ws += (bytes + 255) & ~(size_t)255; return p;
  };
  ushort_t* z0    = (ushort_t*)alloc((size_t)N * EMB * 2);
  ushort_t* hb    = (ushort_t*)alloc((size_t)N * EMB * 2);
  ushort_t* ea2   = (ushort_t*)alloc((size_t)E * ED * 2);
  int*      srcs  = (int*)alloc((size_t)E * 4);
  float*    vn0   = (float*)alloc((size_t)NGRAPH * EMB * 4);
  float*    vn1   = (float*)alloc((size_t)NGRAPH * EMB * 4);
  float*    vt    = (float*)alloc((size_t)NGRAPH * EMB * 4);
  int*      counts = (int*)alloc((size_t)N * 4);
  int*      rankv  = (int*)alloc((size_t)E * 4);
  int*      offs   = (int*)alloc(((size_t)N + 1) * 4);
  int*      bsum   = (int*)alloc(256 * 4);
  int*      boff   = (int*)alloc(256 * 4);
  ushort_t* w1t = (ushort_t*)alloc((size_t)NLAYER * HID * EMB * 2);
  ushort_t* w2t = (ushort_t*)alloc((size_t)NLAYER * EMB * HID * 2);
  float* vnbuf[2] = {vn0, vn1};

  float inv = 1.0f / sqrtf(1.0f + 1e-5f);
  int ntiles = (N + 15) / 16;

  hipMemsetAsync(counts, 0, (size_t)N * 4, stream);
  k_init_vn<<<NGRAPH * EMB / 256, 256, 0, stream>>>(vn0, vn_emb);
  k_transw<<<(NLAYER * EMB * HID + 255) / 256, 256, 0, stream>>>(cw1, cw2, w1t, w2t);
  k_count<<<(E + 255) / 256, 256, 0, stream>>>(dst, counts, rankv, E);
  int nsb = (N + 2047) / 2048;
  k_scanA<<<nsb, 256, 0, stream>>>(counts, offs, bsum, N);
  k_scanB<<<1, 256, 0, stream>>>(bsum, boff, nsb);
  k_scanC<<<(N + 1 + 255) / 256, 256, 0, stream>>>(offs, boff, N, E);
  k_reorder<<<(E + 255) / 256, 256, 0, stream>>>(edge_attr, src, dst, rankv, offs, ea2, srcs, E);

  for (int l = 0; l < NLAYER; l++){
    const float* vnc = vnbuf[l & 1];
    float* vnn = vnbuf[(l + 1) & 1];
    int last = (l == NLAYER - 1) ? 1 : 0;
    if (l == 0)
      k_hin<<<(N * 32 + 255) / 256, 256, 0, stream>>>(in_feat, batch, vnc, hb, N);
    k_agg<<<4096, 256, 0, stream>>>(hb, ea2, srcs, offs,
                                    cew + (size_t)l * ED * EMB, ceb + (size_t)l * EMB, z0, N);
    if (!last){
      hipMemsetAsync(vt, 0, (size_t)NGRAPH * EMB * 4, stream);
      k_vt<<<(N + VT_CHUNK - 1) / VT_CHUNK, 256, 0, stream>>>(hb, batch, vt, N);
      k_vnmlp<<<NGRAPH, HID, 0, stream>>>(vt,
                                          vw1 + (size_t)l * EMB * HID, vb1 + (size_t)l * HID,
                                          vg1 + (size_t)l * HID, vbe1 + (size_t)l * HID,
                                          vw2 + (size_t)l * HID * EMB, vb2 + (size_t)l * EMB,
                                          vg2 + (size_t)l * EMB, vbe2 + (size_t)l * EMB,
                                          vnc, vnn, inv);
    }
    k_mlp<<<1024, 256, 0, stream>>>(z0, w1t + (size_t)l * HID * EMB, cb1 + (size_t)l * HID,
                                    w2t + (size_t)l * EMB * HID, cb2 + (size_t)l * EMB,
                                    bng + (size_t)l * EMB, bnb + (size_t)l * EMB,
                                    hb, batch, vnn, hb, out, inv, last, ntiles);
  }
}